// Round 2
// baseline (78.651 us; speedup 1.0000x reference)
//
#include <hip/hip_runtime.h>

#define MOM 0.9f
#define ONE_MINUS_MOM 0.1f

// K1: per-row argmax of scores (first-max tie-break, matching np.argmax),
// emit key[i] = (label << 1) | (pred != label)
__global__ __launch_bounds__(256) void argmax_key_kernel(
    const float* __restrict__ scores, const int* __restrict__ labels,
    int* __restrict__ key, int C)
{
    const int row = blockIdx.x;
    const float* rp = scores + (size_t)row * C;
    float best = -__builtin_inff();
    int bidx = 0x7fffffff;

    const int nv = C >> 2;
    const float4* r4 = (const float4*)rp;
    for (int v = threadIdx.x; v < nv; v += 256) {
        float4 s = r4[v];
        int b = v << 2;
        if (s.x > best) { best = s.x; bidx = b; }
        if (s.y > best) { best = s.y; bidx = b + 1; }
        if (s.z > best) { best = s.z; bidx = b + 2; }
        if (s.w > best) { best = s.w; bidx = b + 3; }
    }
    for (int c = (nv << 2) + threadIdx.x; c < C; c += 256) {
        float s = rp[c];
        if (s > best) { best = s; bidx = c; }
    }

    __shared__ float sv[256];
    __shared__ int   si[256];
    sv[threadIdx.x] = best;
    si[threadIdx.x] = bidx;
    __syncthreads();
    for (int off = 128; off > 0; off >>= 1) {
        if (threadIdx.x < off) {
            float ov = sv[threadIdx.x + off];
            int   oi = si[threadIdx.x + off];
            float cv = sv[threadIdx.x];
            int   ci = si[threadIdx.x];
            if (ov > cv || (ov == cv && oi < ci)) {
                sv[threadIdx.x] = ov;
                si[threadIdx.x] = oi;
            }
        }
        __syncthreads();
    }
    if (threadIdx.x == 0) {
        int lab = labels[row];
        key[row] = (lab << 1) | ((si[0] != lab) ? 1 : 0);
    }
}

// K2: one wave per sample i. c[i] = # of later chosen samples with same label
// (key equality implies same label AND chosen, since key[i] has LSB set).
// w[i] = (1-m) * m^c[i] for chosen, else 0.
__global__ __launch_bounds__(256) void later_count_kernel(
    const int* __restrict__ key, int* __restrict__ cv, float* __restrict__ wv,
    int B)
{
    const int lane = threadIdx.x & 63;
    const int i = blockIdx.x * 4 + (threadIdx.x >> 6);
    if (i >= B) return;
    const int mykey = key[i];
    int c = 0;
    if (mykey & 1) {
        for (int base = (i + 1) & ~63; base < B; base += 64) {
            int j = base + lane;
            bool match = (j > i) && (j < B) && (key[j] == mykey);
            c += __popcll(__ballot(match));
        }
    }
    if (lane == 0) {
        cv[i] = c;
        float w = 0.0f;
        if (mykey & 1) {
            w = ONE_MINUS_MOM;
            for (int q = 0; q < c; ++q) w *= MOM;
        }
        wv[i] = w;
    }
}

// K3: single block. LDS histogram -> exclusive prefix -> CSR offsets (global)
// -> stable scatter of (sample index, weight) sorted by (class, sample idx).
__global__ __launch_bounds__(256) void build_csr_kernel(
    const int* __restrict__ key, const int* __restrict__ cv,
    const float* __restrict__ wv,
    int* __restrict__ off_g, int* __restrict__ sidx, float* __restrict__ sw,
    int B, int C)
{
    __shared__ int off_s[10001];
    __shared__ int part[256];
    const int tid = threadIdx.x;

    for (int l = tid; l < C; l += 256) off_s[l] = 0;
    __syncthreads();

    for (int i = tid; i < B; i += 256) {
        int kk = key[i];
        if (kk & 1) atomicAdd(&off_s[kk >> 1], 1);
    }
    __syncthreads();

    const int CH = (C + 255) / 256;
    const int base = tid * CH;
    int s = 0;
    if (base < C) {
        int end = base + CH; if (end > C) end = C;
        for (int l = base; l < end; ++l) s += off_s[l];
    }
    part[tid] = s;
    __syncthreads();
    if (tid == 0) {
        int run = 0;
        for (int t = 0; t < 256; ++t) { int v = part[t]; part[t] = run; run += v; }
        off_s[C] = run;
    }
    __syncthreads();
    if (base < C) {
        int run = part[tid];
        int end = base + CH; if (end > C) end = C;
        for (int l = base; l < end; ++l) { int v = off_s[l]; off_s[l] = run; run += v; }
    }
    __syncthreads();

    for (int l = tid; l <= C; l += 256) off_g[l] = off_s[l];
    for (int i = tid; i < B; i += 256) {
        int kk = key[i];
        if (kk & 1) {
            int l = kk >> 1;
            int o0 = off_s[l], o1 = off_s[l + 1];
            int pos = o0 + (o1 - o0 - 1 - cv[i]);   // rank = k-1-c, ascending i
            sidx[pos] = i;
            sw[pos] = wv[i];
        }
    }
}

// K4: one block per class. out = m^k * bank + sum_p w_p * feat[j_p]; no LDS,
// no barriers; list comes from the CSR.
__global__ __launch_bounds__(256) void class_update_kernel(
    const float* __restrict__ bank, const float* __restrict__ times,
    const float* __restrict__ feat, const int* __restrict__ off,
    const int* __restrict__ sidx, const float* __restrict__ sw,
    float* __restrict__ out_bank, float* __restrict__ out_times, int D)
{
    const int l = blockIdx.x;
    const int o0 = off[l], o1 = off[l + 1];
    const int k = o1 - o0;
    float scale = 1.0f;
    for (int p = 0; p < k; ++p) scale *= MOM;

    const int nv = D >> 2;
    const float4* brow = (const float4*)(bank + (size_t)l * D);
    float4* orow = (float4*)(out_bank + (size_t)l * D);
    for (int v = threadIdx.x; v < nv; v += 256) {
        float4 a = brow[v];
        a.x *= scale; a.y *= scale; a.z *= scale; a.w *= scale;
        for (int p = 0; p < k; ++p) {
            int j = sidx[o0 + p];
            float wgt = sw[o0 + p];
            const float4* f4 = (const float4*)(feat + (size_t)j * D);
            float4 f = f4[v];
            a.x += wgt * f.x;
            a.y += wgt * f.y;
            a.z += wgt * f.z;
            a.w += wgt * f.w;
        }
        orow[v] = a;
    }
    if (threadIdx.x == 0) out_times[l] = times[l] + (float)k;
}

extern "C" void kernel_launch(void* const* d_in, const int* in_sizes, int n_in,
                              void* d_out, int out_size, void* d_ws, size_t ws_size,
                              hipStream_t stream) {
    const float* scores = (const float*)d_in[0];
    const float* feat   = (const float*)d_in[1];
    const float* bank   = (const float*)d_in[2];
    const float* times  = (const float*)d_in[3];
    const int*   labels = (const int*)d_in[4];

    const int B = in_sizes[4];            // 4096
    const int C = in_sizes[3];            // 10000
    const int D = in_sizes[1] / B;        // 1024

    float* out_bank  = (float*)d_out;
    float* out_times = out_bank + (size_t)C * D;

    int*   key  = (int*)d_ws;             // B
    int*   cv   = key + B;                // B
    float* wv   = (float*)(cv + B);       // B
    int*   sidx = (int*)(wv + B);         // B
    float* sw   = (float*)(sidx + B);     // B
    int*   off  = (int*)(sw + B);         // C+1

    argmax_key_kernel<<<B, 256, 0, stream>>>(scores, labels, key, C);
    later_count_kernel<<<(B + 3) / 4, 256, 0, stream>>>(key, cv, wv, B);
    build_csr_kernel<<<1, 256, 0, stream>>>(key, cv, wv, off, sidx, sw, B, C);
    class_update_kernel<<<C, 256, 0, stream>>>(bank, times, feat, off, sidx, sw,
                                               out_bank, out_times, D);
}

// Round 3
// 65.506 us; speedup vs baseline: 1.2007x; 1.2007x over previous
//
#include <hip/hip_runtime.h>

#define MOM 0.9f
#define ONE_MINUS_MOM 0.1f
#define MAXK 16

// K1: per-row argmax of scores (first-max tie-break, matching np.argmax),
// emit key[i] = (label << 1) | (pred != label)
__global__ __launch_bounds__(256) void argmax_key_kernel(
    const float* __restrict__ scores, const int* __restrict__ labels,
    int* __restrict__ key, int C)
{
    const int row = blockIdx.x;
    const float* rp = scores + (size_t)row * C;
    float best = -__builtin_inff();
    int bidx = 0x7fffffff;

    const int nv = C >> 2;
    const float4* r4 = (const float4*)rp;
    for (int v = threadIdx.x; v < nv; v += 256) {
        float4 s = r4[v];
        int b = v << 2;
        if (s.x > best) { best = s.x; bidx = b; }
        if (s.y > best) { best = s.y; bidx = b + 1; }
        if (s.z > best) { best = s.z; bidx = b + 2; }
        if (s.w > best) { best = s.w; bidx = b + 3; }
    }
    for (int c = (nv << 2) + threadIdx.x; c < C; c += 256) {
        float s = rp[c];
        if (s > best) { best = s; bidx = c; }
    }

    __shared__ float sv[256];
    __shared__ int   si[256];
    sv[threadIdx.x] = best;
    si[threadIdx.x] = bidx;
    __syncthreads();
    for (int off = 128; off > 0; off >>= 1) {
        if (threadIdx.x < off) {
            float ov = sv[threadIdx.x + off];
            int   oi = si[threadIdx.x + off];
            float cv = sv[threadIdx.x];
            int   ci = si[threadIdx.x];
            if (ov > cv || (ov == cv && oi < ci)) {
                sv[threadIdx.x] = ov;
                si[threadIdx.x] = oi;
            }
        }
        __syncthreads();
    }
    if (threadIdx.x == 0) {
        int lab = labels[row];
        key[row] = (lab << 1) | ((si[0] != lab) ? 1 : 0);
    }
}

// K2: one wave per sample i. One ballot sweep over key[] yields both
//   e = # earlier chosen samples with same label (the sample's rank)
//   c = # later chosen samples with same label
// Chosen sample i goes to slot[class*MAXK + e]; the unique e==0 sample
// writes cnt[class] = e + c + 1. No atomics, no scan, deterministic.
__global__ __launch_bounds__(256) void rank_kernel(
    const int* __restrict__ key, int* __restrict__ cnt,
    int* __restrict__ slot, int B)
{
    const int lane = threadIdx.x & 63;
    const int i = blockIdx.x * 4 + (threadIdx.x >> 6);
    if (i >= B) return;
    const int mykey = key[i];
    if (!(mykey & 1)) return;   // not chosen: contributes nothing

    int e = 0, c = 0;
    for (int base = 0; base < B; base += 64) {
        int j = base + lane;
        int kj = (j < B) ? key[j] : -1;
        bool match = (kj == mykey);
        e += __popcll(__ballot(match && (j < i)));
        c += __popcll(__ballot(match && (j > i)));
    }
    if (lane == 0) {
        int l = mykey >> 1;
        if (e < MAXK) slot[l * MAXK + e] = i;
        if (e == 0) cnt[l] = c + 1;
    }
}

// K3: one block per class. out = m^k * bank + sum_r w_r * feat[slot_r].
// Accumulate ranks descending so the weight is a running multiply:
// w(r=k-1)=0.1, then *=0.9 per step down. No LDS, no barriers.
__global__ __launch_bounds__(256) void update_kernel(
    const float* __restrict__ bank, const float* __restrict__ times,
    const float* __restrict__ feat, const int* __restrict__ cnt,
    const int* __restrict__ slot,
    float* __restrict__ out_bank, float* __restrict__ out_times, int D)
{
    const int l = blockIdx.x;
    const int k = cnt[l];
    const int kk = (k < MAXK) ? k : MAXK;

    float scale = 1.0f;
    for (int p = 0; p < k; ++p) scale *= MOM;

    const int nv = D >> 2;
    const float4* brow = (const float4*)(bank + (size_t)l * D);
    float4* orow = (float4*)(out_bank + (size_t)l * D);
    const int sbase = l * MAXK;

    for (int v = threadIdx.x; v < nv; v += 256) {
        float4 a = brow[v];
        a.x *= scale; a.y *= scale; a.z *= scale; a.w *= scale;
        float wgt = ONE_MINUS_MOM;
        for (int r = kk - 1; r >= 0; --r) {
            int j = slot[sbase + r];
            const float4* f4 = (const float4*)(feat + (size_t)j * D);
            float4 f = f4[v];
            a.x += wgt * f.x;
            a.y += wgt * f.y;
            a.z += wgt * f.z;
            a.w += wgt * f.w;
            wgt *= MOM;
        }
        orow[v] = a;
    }
    if (threadIdx.x == 0) out_times[l] = times[l] + (float)k;
}

extern "C" void kernel_launch(void* const* d_in, const int* in_sizes, int n_in,
                              void* d_out, int out_size, void* d_ws, size_t ws_size,
                              hipStream_t stream) {
    const float* scores = (const float*)d_in[0];
    const float* feat   = (const float*)d_in[1];
    const float* bank   = (const float*)d_in[2];
    const float* times  = (const float*)d_in[3];
    const int*   labels = (const int*)d_in[4];

    const int B = in_sizes[4];            // 4096
    const int C = in_sizes[3];            // 10000
    const int D = in_sizes[1] / B;        // 1024

    float* out_bank  = (float*)d_out;
    float* out_times = out_bank + (size_t)C * D;

    int* key  = (int*)d_ws;               // B
    int* cnt  = key + B;                  // C
    int* slot = cnt + C;                  // C * MAXK

    hipMemsetAsync(cnt, 0, (size_t)C * sizeof(int), stream);
    argmax_key_kernel<<<B, 256, 0, stream>>>(scores, labels, key, C);
    rank_kernel<<<(B + 3) / 4, 256, 0, stream>>>(key, cnt, slot, B);
    update_kernel<<<C, 256, 0, stream>>>(bank, times, feat, cnt, slot,
                                         out_bank, out_times, D);
}

// Round 4
// 61.752 us; speedup vs baseline: 1.2737x; 1.0608x over previous
//
#include <hip/hip_runtime.h>

#define MOM 0.9f
#define ONE_MINUS_MOM 0.1f
#define MAXK 16

// K1: per-row argmax of scores (first-max tie-break, matching np.argmax),
// emit key[i] = (label << 1) | (pred != label).
// Also zero-initializes cnt[] (visible to K2 via stream ordering).
__global__ __launch_bounds__(256) void argmax_key_kernel(
    const float* __restrict__ scores, const int* __restrict__ labels,
    int* __restrict__ key, int* __restrict__ cnt, int C)
{
    // fold the cnt memset into this kernel: 4096 blocks x 4 >= C
    if (threadIdx.x < 4) {
        int l = (blockIdx.x << 2) | threadIdx.x;
        if (l < C) cnt[l] = 0;
    }

    const int row = blockIdx.x;
    const float* rp = scores + (size_t)row * C;
    float best = -__builtin_inff();
    int bidx = 0x7fffffff;

    const int nv = C >> 2;
    const float4* r4 = (const float4*)rp;
    for (int v = threadIdx.x; v < nv; v += 256) {
        float4 s = r4[v];
        int b = v << 2;
        if (s.x > best) { best = s.x; bidx = b; }
        if (s.y > best) { best = s.y; bidx = b + 1; }
        if (s.z > best) { best = s.z; bidx = b + 2; }
        if (s.w > best) { best = s.w; bidx = b + 3; }
    }
    for (int c = (nv << 2) + threadIdx.x; c < C; c += 256) {
        float s = rp[c];
        if (s > best) { best = s; bidx = c; }
    }

    // in-wave butterfly reduce (value desc, index asc tie-break)
    #pragma unroll
    for (int off = 32; off > 0; off >>= 1) {
        float ov = __shfl_xor(best, off);
        int   oi = __shfl_xor(bidx, off);
        if (ov > best || (ov == best && oi < bidx)) { best = ov; bidx = oi; }
    }

    __shared__ float sv[4];
    __shared__ int   si[4];
    const int lane = threadIdx.x & 63;
    const int wid  = threadIdx.x >> 6;
    if (lane == 0) { sv[wid] = best; si[wid] = bidx; }
    __syncthreads();
    if (threadIdx.x == 0) {
        float bv = sv[0]; int bi = si[0];
        #pragma unroll
        for (int w = 1; w < 4; ++w) {
            float ov = sv[w]; int oi = si[w];
            if (ov > bv || (ov == bv && oi < bi)) { bv = ov; bi = oi; }
        }
        int lab = labels[row];
        key[row] = (lab << 1) | ((bi != lab) ? 1 : 0);
    }
}

// K2: one wave per sample i. One ballot sweep over key[] yields both
//   e = # earlier chosen samples with same label (the sample's rank)
//   c = # later chosen samples with same label
// Chosen sample i goes to slot[class*MAXK + e]; the unique e==0 sample
// writes cnt[class] = e + c + 1. No atomics, no scan, deterministic.
__global__ __launch_bounds__(256) void rank_kernel(
    const int* __restrict__ key, int* __restrict__ cnt,
    int* __restrict__ slot, int B)
{
    const int lane = threadIdx.x & 63;
    const int i = blockIdx.x * 4 + (threadIdx.x >> 6);
    if (i >= B) return;
    const int mykey = key[i];
    if (!(mykey & 1)) return;   // not chosen

    int e = 0, c = 0;
    for (int base = 0; base < B; base += 64) {
        int j = base + lane;
        int kj = (j < B) ? key[j] : -1;
        bool match = (kj == mykey);
        e += __popcll(__ballot(match && (j < i)));
        c += __popcll(__ballot(match && (j > i)));
    }
    if (lane == 0) {
        int l = mykey >> 1;
        if (e < MAXK) slot[l * MAXK + e] = i;
        if (e == 0) cnt[l] = c + 1;
    }
}

// K3: one WAVE per class (4 classes/block). Each lane owns 4 float4s of the
// D=1024 row -> 4 independent coalesced 1KB wave-loads in flight, no LDS,
// no barriers. out = m^k * bank + sum_r w_r * feat[slot_r], ranks descending
// so weight is a running multiply.
__global__ __launch_bounds__(256) void update_kernel(
    const float* __restrict__ bank, const float* __restrict__ times,
    const float* __restrict__ feat, const int* __restrict__ cnt,
    const int* __restrict__ slot,
    float* __restrict__ out_bank, float* __restrict__ out_times, int C, int D)
{
    const int lane = threadIdx.x & 63;
    const int wid  = threadIdx.x >> 6;
    const int l = (blockIdx.x << 2) | wid;
    if (l >= C) return;

    const int k = cnt[l];
    const int kk = (k < MAXK) ? k : MAXK;
    float scale = 1.0f;
    for (int p = 0; p < k; ++p) scale *= MOM;

    const float4* brow = (const float4*)(bank + (size_t)l * D);
    float4* orow = (float4*)(out_bank + (size_t)l * D);
    const int sbase = l * MAXK;
    const int nv = D >> 2;

    if (nv == 256) {
        float4 a0 = brow[lane];
        float4 a1 = brow[lane + 64];
        float4 a2 = brow[lane + 128];
        float4 a3 = brow[lane + 192];
        a0.x *= scale; a0.y *= scale; a0.z *= scale; a0.w *= scale;
        a1.x *= scale; a1.y *= scale; a1.z *= scale; a1.w *= scale;
        a2.x *= scale; a2.y *= scale; a2.z *= scale; a2.w *= scale;
        a3.x *= scale; a3.y *= scale; a3.z *= scale; a3.w *= scale;
        float wgt = ONE_MINUS_MOM;
        for (int r = kk - 1; r >= 0; --r) {
            int j = slot[sbase + r];
            const float4* f4 = (const float4*)(feat + (size_t)j * D);
            float4 f0 = f4[lane];
            float4 f1 = f4[lane + 64];
            float4 f2 = f4[lane + 128];
            float4 f3 = f4[lane + 192];
            a0.x += wgt * f0.x; a0.y += wgt * f0.y; a0.z += wgt * f0.z; a0.w += wgt * f0.w;
            a1.x += wgt * f1.x; a1.y += wgt * f1.y; a1.z += wgt * f1.z; a1.w += wgt * f1.w;
            a2.x += wgt * f2.x; a2.y += wgt * f2.y; a2.z += wgt * f2.z; a2.w += wgt * f2.w;
            a3.x += wgt * f3.x; a3.y += wgt * f3.y; a3.z += wgt * f3.z; a3.w += wgt * f3.w;
            wgt *= MOM;
        }
        orow[lane] = a0;
        orow[lane + 64] = a1;
        orow[lane + 128] = a2;
        orow[lane + 192] = a3;
    } else {
        for (int v = lane; v < nv; v += 64) {
            float4 a = brow[v];
            a.x *= scale; a.y *= scale; a.z *= scale; a.w *= scale;
            float wgt = ONE_MINUS_MOM;
            for (int r = kk - 1; r >= 0; --r) {
                int j = slot[sbase + r];
                const float4* f4 = (const float4*)(feat + (size_t)j * D);
                float4 f = f4[v];
                a.x += wgt * f.x; a.y += wgt * f.y; a.z += wgt * f.z; a.w += wgt * f.w;
                wgt *= MOM;
            }
            orow[v] = a;
        }
    }
    if (lane == 0) out_times[l] = times[l] + (float)k;
}

extern "C" void kernel_launch(void* const* d_in, const int* in_sizes, int n_in,
                              void* d_out, int out_size, void* d_ws, size_t ws_size,
                              hipStream_t stream) {
    const float* scores = (const float*)d_in[0];
    const float* feat   = (const float*)d_in[1];
    const float* bank   = (const float*)d_in[2];
    const float* times  = (const float*)d_in[3];
    const int*   labels = (const int*)d_in[4];

    const int B = in_sizes[4];            // 4096
    const int C = in_sizes[3];            // 10000
    const int D = in_sizes[1] / B;        // 1024

    float* out_bank  = (float*)d_out;
    float* out_times = out_bank + (size_t)C * D;

    int* key  = (int*)d_ws;               // B
    int* cnt  = key + B;                  // C
    int* slot = cnt + C;                  // C * MAXK

    argmax_key_kernel<<<B, 256, 0, stream>>>(scores, labels, key, cnt, C);
    rank_kernel<<<(B + 3) / 4, 256, 0, stream>>>(key, cnt, slot, B);
    update_kernel<<<(C + 3) / 4, 256, 0, stream>>>(bank, times, feat, cnt, slot,
                                                   out_bank, out_times, C, D);
}